// Round 3
// baseline (706.071 us; speedup 1.0000x reference)
//
#include <hip/hip_runtime.h>
#include <hip/hip_bf16.h>

typedef float f32x4 __attribute__((ext_vector_type(4)));
typedef short bf16x8 __attribute__((ext_vector_type(8)));
typedef unsigned short ushort;

// 256^2 deep-pipelined GEMM geometry
#define BM 256
#define BN 256
#define BK 64

// ---------- helpers ----------

__device__ inline ushort f2bf(float f) {
    __hip_bfloat16 h = __float2bfloat16(f);   // RNE
    ushort s;
    __builtin_memcpy(&s, &h, 2);
    return s;
}

__device__ inline bf16x8 quant_pack8(float4 a, float4 b, float inv_scale, float zp) {
    float v[8] = {a.x, a.y, a.z, a.w, b.x, b.y, b.z, b.w};
    union { bf16x8 v8; ushort s[8]; } o;
#pragma unroll
    for (int j = 0; j < 8; ++j) {
        float t = rintf(fmaf(v[j], inv_scale, zp));
        t = fminf(127.0f, fmaxf(-128.0f, t));
        o.s[j] = f2bf(t);
    }
    return o.v8;
}

__device__ inline bf16x8 cvt_pack8(float4 a, float4 b) {
    float v[8] = {a.x, a.y, a.z, a.w, b.x, b.y, b.z, b.w};
    union { bf16x8 v8; ushort s[8]; } o;
#pragma unroll
    for (int j = 0; j < 8; ++j) o.s[j] = f2bf(v[j]);
    return o.v8;
}

#define GLL16(gp, lp)                                                              \
    __builtin_amdgcn_global_load_lds(                                              \
        (const __attribute__((address_space(1))) unsigned int*)(gp),               \
        (__attribute__((address_space(3))) unsigned int*)(lp), 16, 0, 0)

// ---------- kernel 1: per-block min/max partials ----------

__global__ __launch_bounds__(256) void minmax_partial(const float* __restrict__ x, int n4,
                                                      float* __restrict__ pmin,
                                                      float* __restrict__ pmax) {
    float lmin = 3.4e38f, lmax = -3.4e38f;
    const float4* xv = (const float4*)x;
    int stride = gridDim.x * blockDim.x;
    for (int i = blockIdx.x * blockDim.x + threadIdx.x; i < n4; i += stride) {
        float4 v = xv[i];
        lmin = fminf(lmin, fminf(fminf(v.x, v.y), fminf(v.z, v.w)));
        lmax = fmaxf(lmax, fmaxf(fmaxf(v.x, v.y), fmaxf(v.z, v.w)));
    }
#pragma unroll
    for (int off = 32; off > 0; off >>= 1) {
        lmin = fminf(lmin, __shfl_down(lmin, off));
        lmax = fmaxf(lmax, __shfl_down(lmax, off));
    }
    __shared__ float smin[4], smax[4];
    int w = threadIdx.x >> 6;
    if ((threadIdx.x & 63) == 0) { smin[w] = lmin; smax[w] = lmax; }
    __syncthreads();
    if (threadIdx.x == 0) {
        pmin[blockIdx.x] = fminf(fminf(smin[0], smin[1]), fminf(smin[2], smin[3]));
        pmax[blockIdx.x] = fmaxf(fmaxf(smax[0], smax[1]), fmaxf(smax[2], smax[3]));
    }
}

// ---------- kernel 2: finalize scale/zp ----------

__global__ __launch_bounds__(64) void finalize_qp(const float* __restrict__ pmin,
                                                  const float* __restrict__ pmax, int nb,
                                                  float* __restrict__ hdr) {
    float lmin = 3.4e38f, lmax = -3.4e38f;
    for (int i = threadIdx.x; i < nb; i += 64) {
        lmin = fminf(lmin, pmin[i]);
        lmax = fmaxf(lmax, pmax[i]);
    }
#pragma unroll
    for (int off = 32; off > 0; off >>= 1) {
        lmin = fminf(lmin, __shfl_down(lmin, off));
        lmax = fmaxf(lmax, __shfl_down(lmax, off));
    }
    if (threadIdx.x == 0) {
        float scale = (lmax - lmin) / 255.0f;
        float zp = -128.0f - rintf(lmin / scale);
        zp = fminf(127.0f, fmaxf(-128.0f, zp));
        hdr[0] = 1.0f / scale;
        hdr[1] = zp;
    }
}

// ---------- kernel 3a: quantize x -> bf16 codes ----------

__global__ __launch_bounds__(256) void quant_x_kernel(const float* __restrict__ x,
                                                      ushort* __restrict__ xq,
                                                      const float* __restrict__ qp, int n8) {
    const float inv_scale = qp[0];
    const float zp = qp[1];
    int stride = gridDim.x * blockDim.x;
    for (int i = blockIdx.x * blockDim.x + threadIdx.x; i < n8; i += stride) {
        float4 a = *(const float4*)(x + (size_t)i * 8);
        float4 b = *(const float4*)(x + (size_t)i * 8 + 4);
        *(bf16x8*)(xq + (size_t)i * 8) = quant_pack8(a, b, inv_scale, zp);
    }
}

// ---------- kernel 3b: convert W -> bf16 ----------

__global__ __launch_bounds__(256) void cvt_w_kernel(const float* __restrict__ w,
                                                    ushort* __restrict__ wq, int n8) {
    int stride = gridDim.x * blockDim.x;
    for (int i = blockIdx.x * blockDim.x + threadIdx.x; i < n8; i += stride) {
        float4 a = *(const float4*)(w + (size_t)i * 8);
        float4 b = *(const float4*)(w + (size_t)i * 8 + 4);
        *(bf16x8*)(wq + (size_t)i * 8) = cvt_pack8(a, b);
    }
}

// ---------- kernel 4: 256x256 deep-pipelined bf16 MFMA GEMM ----------
// C = A(MxK) * B(NxK)^T + bias, A/B bf16.
// 512 threads = 8 waves (2x4), each wave 128x64 output = 8x4 frags 16x16x32.
// LDS [buf][kg][row][8] conflict-free layout; double-buffered; prefetch
// distance 2 K-tiles with counted s_waitcnt vmcnt(8) (T3+T4), setprio (T5).

__global__ __launch_bounds__(512, 2) void gemm_bt(const ushort* __restrict__ A,
                                                  const ushort* __restrict__ Bw,
                                                  const float* __restrict__ bias,
                                                  float* __restrict__ out,
                                                  int M, int N, int K) {
    // per-buffer: 8 kg x 256 rows x 8 ushorts = 16384 ushorts = 32 KB
    __shared__ ushort Alds[2 * 16384];  // 64 KB
    __shared__ ushort Blds[2 * 16384];  // 64 KB

    const int tid = threadIdx.x;
    const int lane = tid & 63;
    const int wid = tid >> 6;

    // bijective XCD swizzle (gridDim.x % 8 == 0: 512)
    const int nwg = gridDim.x;
    const int cpx = nwg >> 3;
    const int swz = (blockIdx.x & 7) * cpx + (blockIdx.x >> 3);
    const int nbn = N / BN;
    const int bm = (swz / nbn) * BM;
    const int bn = (swz % nbn) * BN;

    const int wm = (wid >> 2) * 128;  // wave row offset (2 rows of waves)
    const int wn = (wid & 3) * 64;    // wave col offset (4 cols of waves)
    const int l16 = lane & 15;
    const int l4 = lane >> 4;

    // staging: per K-tile each operand = 2048 chunks of 16B; 512 thr x 4 calls.
    // chunk c: row = c & 255, kg = c >> 8; LDS dst = flat + c*8 (lane-linear
    // within each wave's 64-chunk run -> satisfies wave-uniform-base rule).
    const ushort* pa[4];
    const ushort* pb[4];
#pragma unroll
    for (int i = 0; i < 4; ++i) {
        const int c = i * 512 + tid;
        pa[i] = A  + (size_t)(bm + (c & 255)) * K + (c >> 8) * 8;
        pb[i] = Bw + (size_t)(bn + (c & 255)) * K + (c >> 8) * 8;
    }

    f32x4 acc[8][4];
#pragma unroll
    for (int i = 0; i < 8; ++i)
#pragma unroll
        for (int j = 0; j < 4; ++j) acc[i][j] = (f32x4){0.f, 0.f, 0.f, 0.f};

    const int nk = K / BK;   // 64

    // ---- prologue: stage kt=0 into buf0, kt=1 into buf1 (16 loads in flight)
#pragma unroll
    for (int b = 0; b < 2; ++b) {
        ushort* Ad = Alds + b * 16384;
        ushort* Bd = Blds + b * 16384;
#pragma unroll
        for (int i = 0; i < 4; ++i) {
            GLL16(pa[i], Ad + (i * 512 + tid) * 8);
            pa[i] += BK;
            GLL16(pb[i], Bd + (i * 512 + tid) * 8);
            pb[i] += BK;
        }
    }

    int cur = 0;
    for (int kt = 0; kt < nk; ++kt) {
        // wait for this tile's 8 loads (leave next tile's 8 in flight)
        if (kt + 1 < nk) asm volatile("s_waitcnt vmcnt(8)" ::: "memory");
        else             asm volatile("s_waitcnt vmcnt(0)" ::: "memory");
        __builtin_amdgcn_s_barrier();

        const ushort* Ab = Alds + cur * 16384;
        const ushort* Bb = Blds + cur * 16384;
#pragma unroll
        for (int h = 0; h < 2; ++h) {
            const int kgb = h * 4 + l4;
            bf16x8 af[8], bfr[4];
#pragma unroll
            for (int fi = 0; fi < 8; ++fi)
                af[fi] = *(const bf16x8*)(Ab + (size_t)(kgb * 256 + wm + fi * 16 + l16) * 8);
#pragma unroll
            for (int fj = 0; fj < 4; ++fj)
                bfr[fj] = *(const bf16x8*)(Bb + (size_t)(kgb * 256 + wn + fj * 16 + l16) * 8);
            __builtin_amdgcn_s_setprio(1);
#pragma unroll
            for (int fi = 0; fi < 8; ++fi)
#pragma unroll
                for (int fj = 0; fj < 4; ++fj)
                    acc[fi][fj] = __builtin_amdgcn_mfma_f32_16x16x32_bf16(af[fi], bfr[fj],
                                                                          acc[fi][fj], 0, 0, 0);
            __builtin_amdgcn_s_setprio(0);
        }

        // all waves done reading buf[cur] before restaging it
        __builtin_amdgcn_s_barrier();

        if (kt + 2 < nk) {
            ushort* Ad = Alds + cur * 16384;
            ushort* Bd = Blds + cur * 16384;
#pragma unroll
            for (int i = 0; i < 4; ++i) {
                GLL16(pa[i], Ad + (i * 512 + tid) * 8);
                pa[i] += BK;
                GLL16(pb[i], Bd + (i * 512 + tid) * 8);
                pb[i] += BK;
            }
        }
        cur ^= 1;
    }

    // epilogue: C/D layout col = lane&15, row = (lane>>4)*4 + r
#pragma unroll
    for (int fj = 0; fj < 4; ++fj) {
        const int col = bn + wn + fj * 16 + l16;
        const float bj = bias[col];
#pragma unroll
        for (int fi = 0; fi < 8; ++fi) {
            const int rowb = bm + wm + fi * 16 + l4 * 4;
            float* po = out + (size_t)rowb * N + col;
#pragma unroll
            for (int r = 0; r < 4; ++r) po[(size_t)r * N] = acc[fi][fj][r] + bj;
        }
    }
}

// ---------- fallback: fused quantize+GEMM (128^2, used if ws too small) ----------

__global__ __launch_bounds__(256) void qgemm_fused(const float* __restrict__ x,
                                                   const float* __restrict__ w,
                                                   const float* __restrict__ bias,
                                                   const float* __restrict__ qp,
                                                   float* __restrict__ out,
                                                   int M, int N, int K) {
    __shared__ ushort As[4][128][8];
    __shared__ ushort Bs[4][128][8];

    const int tid = threadIdx.x;
    const int bm = blockIdx.y * 128;
    const int bn = blockIdx.x * 128;
    const float inv_scale = qp[0];
    const float zp = qp[1];
    const int lane = tid & 63;
    const int wid = tid >> 6;
    const int wm = (wid >> 1) * 64;
    const int wn = (wid & 1) * 64;
    const int l16 = lane & 15;
    const int kg = lane >> 4;
    const int r0 = tid >> 2;
    const int g0 = tid & 3;

    const float* pa0 = x + (size_t)(bm + r0) * K + g0 * 8;
    const float* pa1 = pa0 + (size_t)64 * K;
    const float* pb0 = w + (size_t)(bn + r0) * K + g0 * 8;
    const float* pb1 = pb0 + (size_t)64 * K;

    f32x4 acc[4][4];
#pragma unroll
    for (int i = 0; i < 4; ++i)
#pragma unroll
        for (int j = 0; j < 4; ++j) acc[i][j] = (f32x4){0.f, 0.f, 0.f, 0.f};

    const int nk = K / 32;
    for (int kt = 0; kt < nk; ++kt) {
        float4 a00 = *(const float4*)(pa0 + 0);
        float4 a01 = *(const float4*)(pa0 + 4);
        float4 a10 = *(const float4*)(pa1 + 0);
        float4 a11 = *(const float4*)(pa1 + 4);
        float4 b00 = *(const float4*)(pb0 + 0);
        float4 b01 = *(const float4*)(pb0 + 4);
        float4 b10 = *(const float4*)(pb1 + 0);
        float4 b11 = *(const float4*)(pb1 + 4);
        pa0 += 32; pa1 += 32; pb0 += 32; pb1 += 32;

        bf16x8 qa0 = quant_pack8(a00, a01, inv_scale, zp);
        bf16x8 qa1 = quant_pack8(a10, a11, inv_scale, zp);
        bf16x8 wb0 = cvt_pack8(b00, b01);
        bf16x8 wb1 = cvt_pack8(b10, b11);

        __syncthreads();
        *(bf16x8*)&As[g0][r0][0]      = qa0;
        *(bf16x8*)&As[g0][r0 + 64][0] = qa1;
        *(bf16x8*)&Bs[g0][r0][0]      = wb0;
        *(bf16x8*)&Bs[g0][r0 + 64][0] = wb1;
        __syncthreads();

        bf16x8 af[4], bfr[4];
#pragma unroll
        for (int i = 0; i < 4; ++i)
            af[i] = *(const bf16x8*)&As[kg][wm + i * 16 + l16][0];
#pragma unroll
        for (int j = 0; j < 4; ++j)
            bfr[j] = *(const bf16x8*)&Bs[kg][wn + j * 16 + l16][0];
#pragma unroll
        for (int i = 0; i < 4; ++i)
#pragma unroll
            for (int j = 0; j < 4; ++j)
                acc[i][j] = __builtin_amdgcn_mfma_f32_16x16x32_bf16(af[i], bfr[j], acc[i][j], 0, 0, 0);
    }

#pragma unroll
    for (int j = 0; j < 4; ++j) {
        const int col = bn + wn + j * 16 + l16;
        const float bj = bias[col];
#pragma unroll
        for (int i = 0; i < 4; ++i) {
            const int rowb = bm + wm + i * 16 + kg * 4;
            float* po = out + (size_t)rowb * N + col;
#pragma unroll
            for (int r = 0; r < 4; ++r) po[(size_t)r * N] = acc[i][j][r] + bj;
        }
    }
}

// ---------- launch ----------

extern "C" void kernel_launch(void* const* d_in, const int* in_sizes, int n_in,
                              void* d_out, int out_size, void* d_ws, size_t ws_size,
                              hipStream_t stream) {
    const float* x    = (const float*)d_in[0];
    const float* w    = (const float*)d_in[1];
    const float* bias = (const float*)d_in[2];
    float* out = (float*)d_out;
    char* ws = (char*)d_ws;

    const int N = in_sizes[2];            // 4096
    const int K = in_sizes[1] / N;        // 4096
    const int M = in_sizes[0] / K;        // 8192

    const size_t xq_off = 16384;
    const size_t xq_bytes = (size_t)M * K * 2;
    const size_t wq_off = xq_off + xq_bytes;
    const size_t wq_bytes = (size_t)N * K * 2;
    const size_t need = wq_off + wq_bytes;

    float* hdr  = (float*)ws;
    float* pmin = (float*)(ws + 4096);
    float* pmax = (float*)(ws + 8192);

    const int n4 = in_sizes[0] / 4;
    const bool big_ok = (M % BM == 0) && (N % BN == 0) && (K % BK == 0) &&
                        (((M / BM) * (N / BN)) % 8 == 0);

    if (ws_size >= need && big_ok) {
        ushort* xq = (ushort*)(ws + xq_off);
        ushort* wq = (ushort*)(ws + wq_off);

        minmax_partial<<<dim3(1024), dim3(256), 0, stream>>>(x, n4, pmin, pmax);
        finalize_qp<<<dim3(1), dim3(64), 0, stream>>>(pmin, pmax, 1024, hdr);
        quant_x_kernel<<<dim3(2048), dim3(256), 0, stream>>>(x, xq, hdr, in_sizes[0] / 8);
        cvt_w_kernel<<<dim3(1024), dim3(256), 0, stream>>>(w, wq, in_sizes[1] / 8);

        const int nwg = (M / BM) * (N / BN);   // 512
        gemm_bt<<<dim3(nwg), dim3(512), 0, stream>>>(xq, wq, bias, out, M, N, K);
    } else {
        int nb = 1024;
        size_t cap = ws_size / sizeof(float);
        if (cap < (size_t)(4096 + 1024)) {
            long avail = (long)cap - 16;
            nb = avail > 2 ? (int)(avail / 2) : 1;
            pmin = hdr + 16;
            pmax = pmin + nb;
        }
        minmax_partial<<<dim3(nb), dim3(256), 0, stream>>>(x, n4, pmin, pmax);
        finalize_qp<<<dim3(1), dim3(64), 0, stream>>>(pmin, pmax, nb, hdr);
        dim3 grid(N / 128, M / 128);
        qgemm_fused<<<grid, dim3(256), 0, stream>>>(x, w, bias, hdr, out, M, N, K);
    }
}

// Round 4
// 451.710 us; speedup vs baseline: 1.5631x; 1.5631x over previous
//
#include <hip/hip_runtime.h>
#include <hip/hip_bf16.h>

typedef float f32x4 __attribute__((ext_vector_type(4)));
typedef short bf16x8 __attribute__((ext_vector_type(8)));
typedef unsigned short ushort;

// 256^2 8-phase GEMM geometry
#define BM 256
#define BN 256
#define BK 64

// ---------- helpers ----------

__device__ inline ushort f2bf(float f) {
    __hip_bfloat16 h = __float2bfloat16(f);   // RNE
    ushort s;
    __builtin_memcpy(&s, &h, 2);
    return s;
}

__device__ inline bf16x8 quant_pack8(float4 a, float4 b, float inv_scale, float zp) {
    float v[8] = {a.x, a.y, a.z, a.w, b.x, b.y, b.z, b.w};
    union { bf16x8 v8; ushort s[8]; } o;
#pragma unroll
    for (int j = 0; j < 8; ++j) {
        float t = rintf(fmaf(v[j], inv_scale, zp));
        t = fminf(127.0f, fmaxf(-128.0f, t));
        o.s[j] = f2bf(t);
    }
    return o.v8;
}

__device__ inline bf16x8 cvt_pack8(float4 a, float4 b) {
    float v[8] = {a.x, a.y, a.z, a.w, b.x, b.y, b.z, b.w};
    union { bf16x8 v8; ushort s[8]; } o;
#pragma unroll
    for (int j = 0; j < 8; ++j) o.s[j] = f2bf(v[j]);
    return o.v8;
}

#define GLL16(gp, lp)                                                              \
    __builtin_amdgcn_global_load_lds(                                              \
        (const __attribute__((address_space(1))) unsigned int*)(gp),               \
        (__attribute__((address_space(3))) unsigned int*)(lp), 16, 0, 0)

// ---------- kernel 1: per-block min/max partials ----------

__global__ __launch_bounds__(256) void minmax_partial(const float* __restrict__ x, int n4,
                                                      float* __restrict__ pmin,
                                                      float* __restrict__ pmax) {
    float lmin = 3.4e38f, lmax = -3.4e38f;
    const float4* xv = (const float4*)x;
    int stride = gridDim.x * blockDim.x;
    for (int i = blockIdx.x * blockDim.x + threadIdx.x; i < n4; i += stride) {
        float4 v = xv[i];
        lmin = fminf(lmin, fminf(fminf(v.x, v.y), fminf(v.z, v.w)));
        lmax = fmaxf(lmax, fmaxf(fmaxf(v.x, v.y), fmaxf(v.z, v.w)));
    }
#pragma unroll
    for (int off = 32; off > 0; off >>= 1) {
        lmin = fminf(lmin, __shfl_down(lmin, off));
        lmax = fmaxf(lmax, __shfl_down(lmax, off));
    }
    __shared__ float smin[4], smax[4];
    int w = threadIdx.x >> 6;
    if ((threadIdx.x & 63) == 0) { smin[w] = lmin; smax[w] = lmax; }
    __syncthreads();
    if (threadIdx.x == 0) {
        pmin[blockIdx.x] = fminf(fminf(smin[0], smin[1]), fminf(smin[2], smin[3]));
        pmax[blockIdx.x] = fmaxf(fmaxf(smax[0], smax[1]), fmaxf(smax[2], smax[3]));
    }
}

// ---------- kernel 2: finalize scale/zp ----------

__global__ __launch_bounds__(64) void finalize_qp(const float* __restrict__ pmin,
                                                  const float* __restrict__ pmax, int nb,
                                                  float* __restrict__ hdr) {
    float lmin = 3.4e38f, lmax = -3.4e38f;
    for (int i = threadIdx.x; i < nb; i += 64) {
        lmin = fminf(lmin, pmin[i]);
        lmax = fmaxf(lmax, pmax[i]);
    }
#pragma unroll
    for (int off = 32; off > 0; off >>= 1) {
        lmin = fminf(lmin, __shfl_down(lmin, off));
        lmax = fmaxf(lmax, __shfl_down(lmax, off));
    }
    if (threadIdx.x == 0) {
        float scale = (lmax - lmin) / 255.0f;
        float zp = -128.0f - rintf(lmin / scale);
        zp = fminf(127.0f, fmaxf(-128.0f, zp));
        hdr[0] = 1.0f / scale;
        hdr[1] = zp;
    }
}

// ---------- kernel 3a: quantize x -> bf16 codes ----------

__global__ __launch_bounds__(256) void quant_x_kernel(const float* __restrict__ x,
                                                      ushort* __restrict__ xq,
                                                      const float* __restrict__ qp, int n8) {
    const float inv_scale = qp[0];
    const float zp = qp[1];
    int stride = gridDim.x * blockDim.x;
    for (int i = blockIdx.x * blockDim.x + threadIdx.x; i < n8; i += stride) {
        float4 a = *(const float4*)(x + (size_t)i * 8);
        float4 b = *(const float4*)(x + (size_t)i * 8 + 4);
        *(bf16x8*)(xq + (size_t)i * 8) = quant_pack8(a, b, inv_scale, zp);
    }
}

// ---------- kernel 3b: convert W -> bf16 ----------

__global__ __launch_bounds__(256) void cvt_w_kernel(const float* __restrict__ w,
                                                    ushort* __restrict__ wq, int n8) {
    int stride = gridDim.x * blockDim.x;
    for (int i = blockIdx.x * blockDim.x + threadIdx.x; i < n8; i += stride) {
        float4 a = *(const float4*)(w + (size_t)i * 8);
        float4 b = *(const float4*)(w + (size_t)i * 8 + 4);
        *(bf16x8*)(wq + (size_t)i * 8) = cvt_pack8(a, b);
    }
}

// ---------- kernel 4: 256x256 8-phase bf16 MFMA GEMM (T3+T4+T5) ----------
// C = A(MxK) * B(NxK)^T + bias.
// 512 thr = 8 waves (2x4), wave tile 128x64 = 8x4 frags 16x16x32.
// Half-tile = one operand's k-half (A-k0,B-k0,A-k1,B-k1 per K-tile) = 2 loads/thr.
// Phase q of tile t: ks=q>>1, fjp=q&1; 16 MFMA; stages half-tile h=4t+q+7.
// vmcnt(6) once per tile boundary; 2 barriers/phase; setprio around MFMA.
// LDS [buf][kg][row][8] per operand: conflict-free (measured 0 conflicts).

__global__ __launch_bounds__(512, 2) void gemm_bt(const ushort* __restrict__ A,
                                                  const ushort* __restrict__ Bw,
                                                  const float* __restrict__ bias,
                                                  float* __restrict__ out,
                                                  int M, int N, int K) {
    __shared__ ushort Alds[2 * 16384];  // 2 bufs x (8 kg x 256 rows x 8) = 64 KB
    __shared__ ushort Blds[2 * 16384];  // 64 KB

    const int tid = threadIdx.x;
    const int lane = tid & 63;
    const int wid = tid >> 6;

    // bijective XCD swizzle (nwg % 8 == 0 guaranteed by launcher)
    const int nwg = gridDim.x;
    const int cpx = nwg >> 3;
    const int swz = (blockIdx.x & 7) * cpx + (blockIdx.x >> 3);
    const int nbn = N / BN;
    const int bm = (swz / nbn) * BM;
    const int bn = (swz % nbn) * BN;

    const int wm = (wid >> 2) * 128;  // wave row offset
    const int wn = (wid & 3) * 64;    // wave col offset
    const int l16 = lane & 15;
    const int l4 = lane >> 4;

    // staging ownership: chunk c0 = tid (kg_local=tid>>8, row=tid&255), c1 = tid+512
    const int r0 = tid & 255;
    const int kgl0 = tid >> 8;        // 0 or 1; wave-uniform (waves are 64-aligned)
    const ushort* gA = A  + (size_t)(bm + r0) * K + kgl0 * 8;
    const ushort* gB = Bw + (size_t)(bn + r0) * K + kgl0 * 8;
    // LDS dst offset for (kh, kgl, row), in ushorts: (kh*4 + kgl)*2048 + row*8
    const int dst0 = kgl0 * 2048 + r0 * 8;   // + kh*8192; second chunk +4096

    // stage half-tile h: tile th=h>>2, slot=h&3 (0=A-k0,1=B-k0,2=A-k1,3=B-k1)
#define STAGE_HT(h)                                                          \
    {                                                                        \
        const int th_ = (h) >> 2, slot_ = (h) & 3, kh_ = slot_ >> 1;         \
        const int ko_ = th_ * 64 + kh_ * 32;                                 \
        if (slot_ & 1) {                                                     \
            const ushort* s_ = gB + ko_;                                     \
            ushort* d_ = Blds + (th_ & 1) * 16384 + kh_ * 8192 + dst0;       \
            GLL16(s_, d_);                                                   \
            GLL16(s_ + 16, d_ + 4096);                                       \
        } else {                                                             \
            const ushort* s_ = gA + ko_;                                     \
            ushort* d_ = Alds + (th_ & 1) * 16384 + kh_ * 8192 + dst0;       \
            GLL16(s_, d_);                                                   \
            GLL16(s_ + 16, d_ + 4096);                                       \
        }                                                                    \
    }

    f32x4 acc[8][4];
#pragma unroll
    for (int i = 0; i < 8; ++i)
#pragma unroll
        for (int j = 0; j < 4; ++j) acc[i][j] = (f32x4){0.f, 0.f, 0.f, 0.f};

    const int nk = K / BK;        // 64 tiles
    const int htot = 4 * nk;      // total half-tiles

    // ---- prologue: stage h=0..6 (tile0 complete + 3/4 of tile1), wait tile0
#pragma unroll
    for (int h = 0; h < 7; ++h) STAGE_HT(h);
    asm volatile("s_waitcnt vmcnt(6)" ::: "memory");
    __builtin_amdgcn_s_barrier();

    bf16x8 af[8];
    for (int t = 0; t < nk; ++t) {
        const ushort* Ab = Alds + (t & 1) * 16384;
        const ushort* Bb = Blds + (t & 1) * 16384;
#pragma unroll
        for (int q = 0; q < 4; ++q) {
            const int ks = q >> 1;
            const int fjp = q & 1;
            const int kgb = ks * 4 + l4;
            // ds-reads for this phase
            if (fjp == 0) {
#pragma unroll
                for (int fi = 0; fi < 8; ++fi)
                    af[fi] = *(const bf16x8*)(Ab + (size_t)(kgb * 256 + wm + fi * 16 + l16) * 8);
            }
            bf16x8 b0 = *(const bf16x8*)(Bb + (size_t)(kgb * 256 + wn + (fjp * 2 + 0) * 16 + l16) * 8);
            bf16x8 b1 = *(const bf16x8*)(Bb + (size_t)(kgb * 256 + wn + (fjp * 2 + 1) * 16 + l16) * 8);
            // stage one half-tile (one-phase lag behind read frontier)
            {
                const int h = 4 * t + q + 7;
                if (h < htot) STAGE_HT(h);
            }
            __builtin_amdgcn_s_barrier();                        // BARRIER1
            asm volatile("s_waitcnt lgkmcnt(0)" ::: "memory");   // my ds_reads done
            __builtin_amdgcn_sched_barrier(0);
            __builtin_amdgcn_s_setprio(1);
#pragma unroll
            for (int fi = 0; fi < 8; ++fi) {
                acc[fi][fjp * 2 + 0] =
                    __builtin_amdgcn_mfma_f32_16x16x32_bf16(af[fi], b0, acc[fi][fjp * 2 + 0], 0, 0, 0);
                acc[fi][fjp * 2 + 1] =
                    __builtin_amdgcn_mfma_f32_16x16x32_bf16(af[fi], b1, acc[fi][fjp * 2 + 1], 0, 0, 0);
            }
            __builtin_amdgcn_s_setprio(0);
            if (q == 3 && t + 1 < nk) {
                if (t + 2 == nk) asm volatile("s_waitcnt vmcnt(0)" ::: "memory");
                else             asm volatile("s_waitcnt vmcnt(6)" ::: "memory");
            }
            __builtin_amdgcn_s_barrier();                        // BARRIER2
        }
    }
#undef STAGE_HT

    // epilogue: C/D layout col = lane&15, row = (lane>>4)*4 + r
#pragma unroll
    for (int fj = 0; fj < 4; ++fj) {
        const int col = bn + wn + fj * 16 + l16;
        const float bj = bias[col];
#pragma unroll
        for (int fi = 0; fi < 8; ++fi) {
            const int rowb = bm + wm + fi * 16 + l4 * 4;
            float* po = out + (size_t)rowb * N + col;
#pragma unroll
            for (int r = 0; r < 4; ++r) po[(size_t)r * N] = acc[fi][fj][r] + bj;
        }
    }
}

// ---------- fallback: fused quantize+GEMM (128^2, used if ws too small) ----------

__global__ __launch_bounds__(256) void qgemm_fused(const float* __restrict__ x,
                                                   const float* __restrict__ w,
                                                   const float* __restrict__ bias,
                                                   const float* __restrict__ qp,
                                                   float* __restrict__ out,
                                                   int M, int N, int K) {
    __shared__ ushort As[4][128][8];
    __shared__ ushort Bs[4][128][8];

    const int tid = threadIdx.x;
    const int bm = blockIdx.y * 128;
    const int bn = blockIdx.x * 128;
    const float inv_scale = qp[0];
    const float zp = qp[1];
    const int lane = tid & 63;
    const int wid = tid >> 6;
    const int wm = (wid >> 1) * 64;
    const int wn = (wid & 1) * 64;
    const int l16 = lane & 15;
    const int kg = lane >> 4;
    const int r0 = tid >> 2;
    const int g0 = tid & 3;

    const float* pa0 = x + (size_t)(bm + r0) * K + g0 * 8;
    const float* pa1 = pa0 + (size_t)64 * K;
    const float* pb0 = w + (size_t)(bn + r0) * K + g0 * 8;
    const float* pb1 = pb0 + (size_t)64 * K;

    f32x4 acc[4][4];
#pragma unroll
    for (int i = 0; i < 4; ++i)
#pragma unroll
        for (int j = 0; j < 4; ++j) acc[i][j] = (f32x4){0.f, 0.f, 0.f, 0.f};

    const int nk = K / 32;
    for (int kt = 0; kt < nk; ++kt) {
        float4 a00 = *(const float4*)(pa0 + 0);
        float4 a01 = *(const float4*)(pa0 + 4);
        float4 a10 = *(const float4*)(pa1 + 0);
        float4 a11 = *(const float4*)(pa1 + 4);
        float4 b00 = *(const float4*)(pb0 + 0);
        float4 b01 = *(const float4*)(pb0 + 4);
        float4 b10 = *(const float4*)(pb1 + 0);
        float4 b11 = *(const float4*)(pb1 + 4);
        pa0 += 32; pa1 += 32; pb0 += 32; pb1 += 32;

        bf16x8 qa0 = quant_pack8(a00, a01, inv_scale, zp);
        bf16x8 qa1 = quant_pack8(a10, a11, inv_scale, zp);
        bf16x8 wb0 = cvt_pack8(b00, b01);
        bf16x8 wb1 = cvt_pack8(b10, b11);

        __syncthreads();
        *(bf16x8*)&As[g0][r0][0]      = qa0;
        *(bf16x8*)&As[g0][r0 + 64][0] = qa1;
        *(bf16x8*)&Bs[g0][r0][0]      = wb0;
        *(bf16x8*)&Bs[g0][r0 + 64][0] = wb1;
        __syncthreads();

        bf16x8 af[4], bfr[4];
#pragma unroll
        for (int i = 0; i < 4; ++i)
            af[i] = *(const bf16x8*)&As[kg][wm + i * 16 + l16][0];
#pragma unroll
        for (int j = 0; j < 4; ++j)
            bfr[j] = *(const bf16x8*)&Bs[kg][wn + j * 16 + l16][0];
#pragma unroll
        for (int i = 0; i < 4; ++i)
#pragma unroll
            for (int j = 0; j < 4; ++j)
                acc[i][j] = __builtin_amdgcn_mfma_f32_16x16x32_bf16(af[i], bfr[j], acc[i][j], 0, 0, 0);
    }

#pragma unroll
    for (int j = 0; j < 4; ++j) {
        const int col = bn + wn + j * 16 + l16;
        const float bj = bias[col];
#pragma unroll
        for (int i = 0; i < 4; ++i) {
            const int rowb = bm + wm + i * 16 + kg * 4;
            float* po = out + (size_t)rowb * N + col;
#pragma unroll
            for (int r = 0; r < 4; ++r) po[(size_t)r * N] = acc[i][j][r] + bj;
        }
    }
}

// ---------- launch ----------

extern "C" void kernel_launch(void* const* d_in, const int* in_sizes, int n_in,
                              void* d_out, int out_size, void* d_ws, size_t ws_size,
                              hipStream_t stream) {
    const float* x    = (const float*)d_in[0];
    const float* w    = (const float*)d_in[1];
    const float* bias = (const float*)d_in[2];
    float* out = (float*)d_out;
    char* ws = (char*)d_ws;

    const int N = in_sizes[2];            // 4096
    const int K = in_sizes[1] / N;        // 4096
    const int M = in_sizes[0] / K;        // 8192

    const size_t xq_off = 16384;
    const size_t xq_bytes = (size_t)M * K * 2;
    const size_t wq_off = xq_off + xq_bytes;
    const size_t wq_bytes = (size_t)N * K * 2;
    const size_t need = wq_off + wq_bytes;

    float* hdr  = (float*)ws;
    float* pmin = (float*)(ws + 4096);
    float* pmax = (float*)(ws + 8192);

    const int n4 = in_sizes[0] / 4;
    const bool big_ok = (M % BM == 0) && (N % BN == 0) && (K % BK == 0) && (K / BK >= 2) &&
                        (((M / BM) * (N / BN)) % 8 == 0);

    if (ws_size >= need && big_ok) {
        ushort* xq = (ushort*)(ws + xq_off);
        ushort* wq = (ushort*)(ws + wq_off);

        minmax_partial<<<dim3(1024), dim3(256), 0, stream>>>(x, n4, pmin, pmax);
        finalize_qp<<<dim3(1), dim3(64), 0, stream>>>(pmin, pmax, 1024, hdr);
        quant_x_kernel<<<dim3(2048), dim3(256), 0, stream>>>(x, xq, hdr, in_sizes[0] / 8);
        cvt_w_kernel<<<dim3(1024), dim3(256), 0, stream>>>(w, wq, in_sizes[1] / 8);

        const int nwg = (M / BM) * (N / BN);   // 512
        gemm_bt<<<dim3(nwg), dim3(512), 0, stream>>>(xq, wq, bias, out, M, N, K);
    } else {
        int nb = 1024;
        size_t cap = ws_size / sizeof(float);
        if (cap < (size_t)(4096 + 1024)) {
            long avail = (long)cap - 16;
            nb = avail > 2 ? (int)(avail / 2) : 1;
            pmin = hdr + 16;
            pmax = pmin + nb;
        }
        minmax_partial<<<dim3(nb), dim3(256), 0, stream>>>(x, n4, pmin, pmax);
        finalize_qp<<<dim3(1), dim3(64), 0, stream>>>(pmin, pmax, nb, hdr);
        dim3 grid(N / 128, M / 128);
        qgemm_fused<<<grid, dim3(256), 0, stream>>>(x, w, bias, hdr, out, M, N, K);
    }
}